// Round 1
// baseline (1323.933 us; speedup 1.0000x reference)
//
#include <hip/hip_runtime.h>
#include <hip/hip_bf16.h>

#define DIM   1024
#define NTOK  8192

using bf16 = __hip_bfloat16;
typedef __attribute__((ext_vector_type(8))) short bf16x8;
typedef __attribute__((ext_vector_type(4))) float f32x4;

__device__ __forceinline__ unsigned short f2b(float x) {
  union { __hip_bfloat16 h; unsigned short u; } cv;
  cv.h = __float2bfloat16(x);
  return cv.u;
}

// ---------------- cast f32 -> bf16 (vectorized float4 -> 4x bf16) ----------------
__global__ __launch_bounds__(256) void cast_f32_bf16(const float* __restrict__ in,
                                                     bf16* __restrict__ out, int n4) {
  int i = blockIdx.x * 256 + threadIdx.x;
  if (i < n4) {
    const float4 v = ((const float4*)in)[i];
    ushort4 p;
    p.x = f2b(v.x); p.y = f2b(v.y); p.z = f2b(v.z); p.w = f2b(v.w);
    ((ushort4*)out)[i] = p;
  }
}

// ---------------- transpose + cast: in[R][C] f32 -> out[C][R] bf16 ----------------
__global__ __launch_bounds__(256) void transpose_cast(const float* __restrict__ in,
                                                      bf16* __restrict__ out, int R, int C) {
  int idx = blockIdx.x * 256 + threadIdx.x;
  if (idx < R * C) {
    int r = idx / C, c = idx % C;
    out[(size_t)c * R + r] = __float2bfloat16(in[idx]);
  }
}

// ---------------- NT GEMM: C[M,N] = A[M,K] @ Bt[N,K]^T (+ epilogue) ----------------
// 128x128 tile, BK=32, 256 threads = 4 waves in 2x2, each wave owns 64x64 (4x4 frags).
// EPI: 0 = (acc+bias) -> bf16 row-major ld N
//      1 = (acc+bias) -> bf16 TRANSPOSED: Cb[c*M + r]
//      2 = sigmoid(acc*scale) -> f32 row-major ld N
//      3 = acc -> f32 row-major ld N
// A_F32: A operand read as f32 and converted to bf16 during staging (for PV from probs).
template<int EPI, bool A_F32>
__global__ __launch_bounds__(256) void gemm_nt(
    const void* __restrict__ Ap, const bf16* __restrict__ Bt,
    int M, int N, int K,
    const float* __restrict__ bias, float scale,
    float* __restrict__ Cf, bf16* __restrict__ Cb)
{
  __shared__ bf16 As[128 * 32];
  __shared__ bf16 Bs[128 * 32];
  const int tid  = threadIdx.x;
  const int lane = tid & 63, wid = tid >> 6;
  const int wr = wid >> 1, wc = wid & 1;
  const int bm = blockIdx.y * 128, bn = blockIdx.x * 128;
  f32x4 acc[4][4] = {};

  const bf16*  Ab16 = (const bf16*)Ap;
  const float* Af32 = (const float*)Ap;

  const int srow = tid >> 2;        // bf16 staging: 64 rows/issue, 2 issues
  const int sc8  = (tid & 3) * 8;   // 8-elem column group
  const int frow = tid >> 3;        // f32 staging: 32 rows/issue, 4 issues
  const int fc4  = (tid & 7) * 4;

  for (int k0 = 0; k0 < K; k0 += 32) {
    // ---- stage A tile (128 x 32) ----
    if (A_F32) {
      #pragma unroll
      for (int is = 0; is < 4; ++is) {
        int row = is * 32 + frow;
        const float4 v = *(const float4*)(Af32 + (size_t)(bm + row) * K + k0 + fc4);
        ushort4 p;
        p.x = f2b(v.x); p.y = f2b(v.y); p.z = f2b(v.z); p.w = f2b(v.w);
        *(ushort4*)(&As[row * 32 + fc4]) = p;
      }
    } else {
      #pragma unroll
      for (int is = 0; is < 2; ++is) {
        int row = is * 64 + srow;
        const bf16* g = Ab16 + (size_t)(bm + row) * K + k0 + sc8;
        __builtin_amdgcn_global_load_lds(
            (const __attribute__((address_space(1))) unsigned int*)g,
            (__attribute__((address_space(3))) unsigned int*)(&As[row * 32 + sc8]),
            16, 0, 0);
      }
    }
    // ---- stage B tile (128 x 32) ----
    #pragma unroll
    for (int is = 0; is < 2; ++is) {
      int row = is * 64 + srow;
      const bf16* g = Bt + (size_t)(bn + row) * K + k0 + sc8;
      __builtin_amdgcn_global_load_lds(
          (const __attribute__((address_space(1))) unsigned int*)g,
          (__attribute__((address_space(3))) unsigned int*)(&Bs[row * 32 + sc8]),
          16, 0, 0);
    }
    __syncthreads();

    // ---- fragments + MFMA ----
    const int lr = lane & 15, kg = lane >> 4;
    bf16x8 af[4], bfv[4];
    #pragma unroll
    for (int i = 0; i < 4; ++i)
      af[i] = *(const bf16x8*)(&As[(wr * 64 + i * 16 + lr) * 32 + kg * 8]);
    #pragma unroll
    for (int j = 0; j < 4; ++j)
      bfv[j] = *(const bf16x8*)(&Bs[(wc * 64 + j * 16 + lr) * 32 + kg * 8]);
    #pragma unroll
    for (int i = 0; i < 4; ++i)
      #pragma unroll
      for (int j = 0; j < 4; ++j)
        acc[i][j] = __builtin_amdgcn_mfma_f32_16x16x32_bf16(af[i], bfv[j], acc[i][j], 0, 0, 0);
    __syncthreads();
  }

  // ---- epilogue ----
  const int r0 = bm + wr * 64 + (lane >> 4) * 4;
  const int c0 = bn + wc * 64 + (lane & 15);

  if (EPI == 0) {
    #pragma unroll
    for (int i = 0; i < 4; ++i) {
      int r = r0 + i * 16;
      #pragma unroll
      for (int j = 0; j < 4; ++j) {
        int c = c0 + j * 16;
        float b = bias[c];
        #pragma unroll
        for (int e = 0; e < 4; ++e)
          Cb[(size_t)(r + e) * N + c] = __float2bfloat16(acc[i][j][e] + b);
      }
    }
  } else if (EPI == 1) {
    #pragma unroll
    for (int j = 0; j < 4; ++j) {
      int c = c0 + j * 16;
      float b = bias[c];
      #pragma unroll
      for (int i = 0; i < 4; ++i) {
        ushort4 p;
        p.x = f2b(acc[i][j][0] + b);
        p.y = f2b(acc[i][j][1] + b);
        p.z = f2b(acc[i][j][2] + b);
        p.w = f2b(acc[i][j][3] + b);
        *(ushort4*)(&Cb[(size_t)c * M + (r0 + i * 16)]) = p;
      }
    }
  } else if (EPI == 2) {
    #pragma unroll
    for (int i = 0; i < 4; ++i) {
      int r = r0 + i * 16;
      #pragma unroll
      for (int j = 0; j < 4; ++j) {
        int c = c0 + j * 16;
        #pragma unroll
        for (int e = 0; e < 4; ++e) {
          float pr = 1.0f / (1.0f + __expf(-acc[i][j][e] * scale));
          Cf[(size_t)(r + e) * N + c] = pr;
        }
      }
    }
  } else {
    #pragma unroll
    for (int i = 0; i < 4; ++i) {
      int r = r0 + i * 16;
      #pragma unroll
      for (int j = 0; j < 4; ++j) {
        int c = c0 + j * 16;
        #pragma unroll
        for (int e = 0; e < 4; ++e)
          Cf[(size_t)(r + e) * N + c] = acc[i][j][e];
      }
    }
  }
}

extern "C" void kernel_launch(void* const* d_in, const int* in_sizes, int n_in,
                              void* d_out, int out_size, void* d_ws, size_t ws_size,
                              hipStream_t stream) {
  const float* x1 = (const float*)d_in[0];
  const float* x2 = (const float*)d_in[1];
  // order: Wq1,bq1, Wk1,bk1, Wv1,bv1, Wq2,bq2, Wk2,bk2, Wv2,bv2
  const float* W[6] = { (const float*)d_in[2],  (const float*)d_in[4],  (const float*)d_in[6],
                        (const float*)d_in[8],  (const float*)d_in[10], (const float*)d_in[12] };
  const float* B[6] = { (const float*)d_in[3],  (const float*)d_in[5],  (const float*)d_in[7],
                        (const float*)d_in[9],  (const float*)d_in[11], (const float*)d_in[13] };

  const size_t MD = (size_t)NTOK * DIM;          // 8M elements
  const size_t DD = (size_t)DIM * DIM;           // 1M elements
  const size_t NN = (size_t)NTOK * NTOK;         // 64M elements

  bf16* ws  = (bf16*)d_ws;
  bf16* x1b = ws;                 // 8M
  bf16* x2b = x1b + MD;           // 8M
  bf16* Wt  = x2b + MD;           // 6 x 1M
  bf16* q1  = Wt + 6 * DD;        // 8M each below
  bf16* k1  = q1 + MD;
  bf16* v1T = k1 + MD;
  bf16* q2  = v1T + MD;
  bf16* k2  = q2 + MD;
  bf16* v2T = k2 + MD;            // total 70M bf16 = 140 MB

  float* out    = (float*)d_out;
  float* ctx2   = out;            // [8192,1024]
  float* probs2 = ctx2 + MD;      // [8192,8192]
  float* ctx1   = probs2 + NN;    // [8192,1024]
  float* probs1 = ctx1 + MD;      // [8192,8192]

  const float scale = 1.0f / 32.0f;   // 1/sqrt(1024)

  // casts
  {
    int n4 = (int)(MD / 4);
    int blks = (n4 + 255) / 256;
    cast_f32_bf16<<<blks, 256, 0, stream>>>(x1, x1b, n4);
    cast_f32_bf16<<<blks, 256, 0, stream>>>(x2, x2b, n4);
  }
  {
    int n = (int)DD;
    int blks = (n + 255) / 256;
    for (int i = 0; i < 6; ++i)
      transpose_cast<<<blks, 256, 0, stream>>>(W[i], Wt + i * DD, DIM, DIM);
  }

  // projections: M=8192, N=1024, K=1024
  dim3 gp(DIM / 128, NTOK / 128);
  gemm_nt<0, false><<<gp, 256, 0, stream>>>(x1b, Wt + 0 * DD, NTOK, DIM, DIM, B[0], 0.f, nullptr, q1);
  gemm_nt<0, false><<<gp, 256, 0, stream>>>(x1b, Wt + 1 * DD, NTOK, DIM, DIM, B[1], 0.f, nullptr, k1);
  gemm_nt<1, false><<<gp, 256, 0, stream>>>(x1b, Wt + 2 * DD, NTOK, DIM, DIM, B[2], 0.f, nullptr, v1T);
  gemm_nt<0, false><<<gp, 256, 0, stream>>>(x2b, Wt + 3 * DD, NTOK, DIM, DIM, B[3], 0.f, nullptr, q2);
  gemm_nt<0, false><<<gp, 256, 0, stream>>>(x2b, Wt + 4 * DD, NTOK, DIM, DIM, B[4], 0.f, nullptr, k2);
  gemm_nt<1, false><<<gp, 256, 0, stream>>>(x2b, Wt + 5 * DD, NTOK, DIM, DIM, B[5], 0.f, nullptr, v2T);

  // attention GEMMs
  dim3 gs(NTOK / 128, NTOK / 128);   // 64 x 64
  // probs2 = sigmoid(scale * q1 @ k2^T)
  gemm_nt<2, false><<<gs, 256, 0, stream>>>(q1, k2, NTOK, NTOK, DIM, nullptr, scale, probs2, nullptr);
  // ctx2 = probs2 @ v2   (A read as f32 from d_out, converted during staging)
  gemm_nt<3, true><<<gp, 256, 0, stream>>>(probs2, v2T, NTOK, DIM, NTOK, nullptr, 0.f, ctx2, nullptr);
  // probs1 = sigmoid(scale * q2 @ k1^T)
  gemm_nt<2, false><<<gs, 256, 0, stream>>>(q2, k1, NTOK, NTOK, DIM, nullptr, scale, probs1, nullptr);
  // ctx1 = probs1 @ v1
  gemm_nt<3, true><<<gp, 256, 0, stream>>>(probs1, v1T, NTOK, DIM, NTOK, nullptr, 0.f, ctx1, nullptr);
}

// Round 2
// 1211.524 us; speedup vs baseline: 1.0928x; 1.0928x over previous
//
#include <hip/hip_runtime.h>
#include <hip/hip_bf16.h>

#define DIM   1024
#define NTOK  8192

using bf16 = __hip_bfloat16;
typedef __attribute__((ext_vector_type(8))) short bf16x8;
typedef __attribute__((ext_vector_type(4))) float f32x4;

__device__ __forceinline__ unsigned short f2b(float x) {
  union { __hip_bfloat16 h; unsigned short u; } cv;
  cv.h = __float2bfloat16(x);
  return cv.u;
}

// ---------------- cast f32 -> bf16 (vectorized float4 -> 4x bf16) ----------------
__global__ __launch_bounds__(256) void cast_f32_bf16(const float* __restrict__ in,
                                                     bf16* __restrict__ out, int n4) {
  int i = blockIdx.x * 256 + threadIdx.x;
  if (i < n4) {
    const float4 v = ((const float4*)in)[i];
    ushort4 p;
    p.x = f2b(v.x); p.y = f2b(v.y); p.z = f2b(v.z); p.w = f2b(v.w);
    ((ushort4*)out)[i] = p;
  }
}

// ------------- tiled transpose + cast: in[R][C] f32 -> out[C][R] bf16 -------------
// 32x32 tiles via LDS, coalesced reads and writes. block = 256 (32x8).
__global__ __launch_bounds__(256) void transpose_cast32(const float* __restrict__ in,
                                                        bf16* __restrict__ out, int R, int C) {
  __shared__ float t[32][33];
  const int tilesC = C / 32;
  const int c0 = (blockIdx.x % tilesC) * 32;
  const int r0 = (blockIdx.x / tilesC) * 32;
  const int tx = threadIdx.x & 31, ty = threadIdx.x >> 5;
  #pragma unroll
  for (int i = 0; i < 4; ++i) {
    int r = ty + i * 8;
    t[r][tx] = in[(size_t)(r0 + r) * C + c0 + tx];
  }
  __syncthreads();
  #pragma unroll
  for (int i = 0; i < 4; ++i) {
    int cr = ty + i * 8;  // output row = input column
    out[(size_t)(c0 + cr) * R + r0 + tx] = __float2bfloat16(t[tx][cr]);
  }
}

// ---------------- NT GEMM: C[M,N] = A[M,K] @ Bt[N,K]^T (+ epilogue) ----------------
// 128x128 tile, BK=32, 256 threads = 4 waves in 2x2, each wave owns 64x64 (4x4 frags).
// 1-D grid with XCD-aware bijective swizzle (requires nwg % 8 == 0, guarded).
// EPI: 0 = (acc+bias) -> bf16 row-major ld N
//      1 = (acc+bias) -> bf16 TRANSPOSED: Cb[c*M + r]
//      2 = sigmoid(acc*scale) -> f32 row-major ld N
//      3 = acc -> f32 row-major ld N
//      4 = sigmoid(acc*scale) -> f32 row-major (Cf) AND bf16 row-major (Cb)
// A_F32: A operand read as f32 and converted to bf16 during staging (fallback).
template<int EPI, bool A_F32>
__global__ __launch_bounds__(256) void gemm_nt(
    const void* __restrict__ Ap, const bf16* __restrict__ Bt,
    int M, int N, int K,
    const float* __restrict__ bias, float scale,
    float* __restrict__ Cf, bf16* __restrict__ Cb)
{
  __shared__ bf16 As[128 * 32];
  __shared__ bf16 Bs[128 * 32];
  const int tid  = threadIdx.x;
  const int lane = tid & 63, wid = tid >> 6;
  const int wr = wid >> 1, wc = wid & 1;

  // XCD-aware swizzle over linear block id
  const int tilesN = N >> 7;
  const int nwg = gridDim.x;
  int bid = blockIdx.x;
  if ((nwg & 7) == 0) {
    const int q = nwg >> 3;
    bid = (bid & 7) * q + (bid >> 3);
  }
  const int bm = (bid / tilesN) * 128, bn = (bid % tilesN) * 128;

  f32x4 acc[4][4] = {};

  const bf16*  Ab16 = (const bf16*)Ap;
  const float* Af32 = (const float*)Ap;

  const int srow = tid >> 2;        // bf16 staging: 64 rows/issue, 2 issues
  const int sc8  = (tid & 3) * 8;   // 8-elem column group
  const int frow = tid >> 3;        // f32 staging: 32 rows/issue, 4 issues
  const int fc4  = (tid & 7) * 4;

  for (int k0 = 0; k0 < K; k0 += 32) {
    // ---- stage A tile (128 x 32) ----
    if (A_F32) {
      #pragma unroll
      for (int is = 0; is < 4; ++is) {
        int row = is * 32 + frow;
        const float4 v = *(const float4*)(Af32 + (size_t)(bm + row) * K + k0 + fc4);
        ushort4 p;
        p.x = f2b(v.x); p.y = f2b(v.y); p.z = f2b(v.z); p.w = f2b(v.w);
        *(ushort4*)(&As[row * 32 + fc4]) = p;
      }
    } else {
      #pragma unroll
      for (int is = 0; is < 2; ++is) {
        int row = is * 64 + srow;
        const bf16* g = Ab16 + (size_t)(bm + row) * K + k0 + sc8;
        __builtin_amdgcn_global_load_lds(
            (const __attribute__((address_space(1))) unsigned int*)g,
            (__attribute__((address_space(3))) unsigned int*)(&As[row * 32 + sc8]),
            16, 0, 0);
      }
    }
    // ---- stage B tile (128 x 32) ----
    #pragma unroll
    for (int is = 0; is < 2; ++is) {
      int row = is * 64 + srow;
      const bf16* g = Bt + (size_t)(bn + row) * K + k0 + sc8;
      __builtin_amdgcn_global_load_lds(
          (const __attribute__((address_space(1))) unsigned int*)g,
          (__attribute__((address_space(3))) unsigned int*)(&Bs[row * 32 + sc8]),
          16, 0, 0);
    }
    __syncthreads();

    // ---- fragments + MFMA ----
    const int lr = lane & 15, kg = lane >> 4;
    bf16x8 af[4], bfv[4];
    #pragma unroll
    for (int i = 0; i < 4; ++i)
      af[i] = *(const bf16x8*)(&As[(wr * 64 + i * 16 + lr) * 32 + kg * 8]);
    #pragma unroll
    for (int j = 0; j < 4; ++j)
      bfv[j] = *(const bf16x8*)(&Bs[(wc * 64 + j * 16 + lr) * 32 + kg * 8]);
    #pragma unroll
    for (int i = 0; i < 4; ++i)
      #pragma unroll
      for (int j = 0; j < 4; ++j)
        acc[i][j] = __builtin_amdgcn_mfma_f32_16x16x32_bf16(af[i], bfv[j], acc[i][j], 0, 0, 0);
    __syncthreads();
  }

  // ---- epilogue ----
  const int r0 = bm + wr * 64 + (lane >> 4) * 4;
  const int c0 = bn + wc * 64 + (lane & 15);

  if (EPI == 0) {
    #pragma unroll
    for (int i = 0; i < 4; ++i) {
      int r = r0 + i * 16;
      #pragma unroll
      for (int j = 0; j < 4; ++j) {
        int c = c0 + j * 16;
        float b = bias[c];
        #pragma unroll
        for (int e = 0; e < 4; ++e)
          Cb[(size_t)(r + e) * N + c] = __float2bfloat16(acc[i][j][e] + b);
      }
    }
  } else if (EPI == 1) {
    #pragma unroll
    for (int j = 0; j < 4; ++j) {
      int c = c0 + j * 16;
      float b = bias[c];
      #pragma unroll
      for (int i = 0; i < 4; ++i) {
        ushort4 p;
        p.x = f2b(acc[i][j][0] + b);
        p.y = f2b(acc[i][j][1] + b);
        p.z = f2b(acc[i][j][2] + b);
        p.w = f2b(acc[i][j][3] + b);
        *(ushort4*)(&Cb[(size_t)c * M + (r0 + i * 16)]) = p;
      }
    }
  } else if (EPI == 2) {
    #pragma unroll
    for (int i = 0; i < 4; ++i) {
      int r = r0 + i * 16;
      #pragma unroll
      for (int j = 0; j < 4; ++j) {
        int c = c0 + j * 16;
        #pragma unroll
        for (int e = 0; e < 4; ++e) {
          float pr = 1.0f / (1.0f + __expf(-acc[i][j][e] * scale));
          Cf[(size_t)(r + e) * N + c] = pr;
        }
      }
    }
  } else if (EPI == 3) {
    #pragma unroll
    for (int i = 0; i < 4; ++i) {
      int r = r0 + i * 16;
      #pragma unroll
      for (int j = 0; j < 4; ++j) {
        int c = c0 + j * 16;
        #pragma unroll
        for (int e = 0; e < 4; ++e)
          Cf[(size_t)(r + e) * N + c] = acc[i][j][e];
      }
    }
  } else {  // EPI == 4: sigmoid -> f32 + bf16
    #pragma unroll
    for (int i = 0; i < 4; ++i) {
      int r = r0 + i * 16;
      #pragma unroll
      for (int j = 0; j < 4; ++j) {
        int c = c0 + j * 16;
        #pragma unroll
        for (int e = 0; e < 4; ++e) {
          float pr = 1.0f / (1.0f + __expf(-acc[i][j][e] * scale));
          Cf[(size_t)(r + e) * N + c] = pr;
          Cb[(size_t)(r + e) * N + c] = __float2bfloat16(pr);
        }
      }
    }
  }
}

extern "C" void kernel_launch(void* const* d_in, const int* in_sizes, int n_in,
                              void* d_out, int out_size, void* d_ws, size_t ws_size,
                              hipStream_t stream) {
  const float* x1 = (const float*)d_in[0];
  const float* x2 = (const float*)d_in[1];
  // order: Wq1,bq1, Wk1,bk1, Wv1,bv1, Wq2,bq2, Wk2,bk2, Wv2,bv2
  const float* W[6] = { (const float*)d_in[2],  (const float*)d_in[4],  (const float*)d_in[6],
                        (const float*)d_in[8],  (const float*)d_in[10], (const float*)d_in[12] };
  const float* B[6] = { (const float*)d_in[3],  (const float*)d_in[5],  (const float*)d_in[7],
                        (const float*)d_in[9],  (const float*)d_in[11], (const float*)d_in[13] };

  const size_t MD = (size_t)NTOK * DIM;          // 8M elements
  const size_t DD = (size_t)DIM * DIM;           // 1M elements
  const size_t NN = (size_t)NTOK * NTOK;         // 64M elements

  bf16* ws  = (bf16*)d_ws;
  bf16* x1b = ws;                 // 8M
  bf16* x2b = x1b + MD;           // 8M
  bf16* Wt  = x2b + MD;           // 6 x 1M
  bf16* q1  = Wt + 6 * DD;        // 8M each below
  bf16* k1  = q1 + MD;
  bf16* v1T = k1 + MD;
  bf16* q2  = v1T + MD;
  bf16* k2  = q2 + MD;
  bf16* v2T = k2 + MD;            // base total: 73.4M bf16 ≈ 147 MB
  bf16* probsb = v2T + MD;        // + 64M bf16 = 128 MB (shared by both directions)

  const size_t need_bytes = ((size_t)(8 * MD + 6 * DD) + NN) * sizeof(bf16);
  const bool probs_bf16 = (ws_size >= need_bytes);

  float* out    = (float*)d_out;
  float* ctx2   = out;            // [8192,1024]
  float* probs2 = ctx2 + MD;      // [8192,8192]
  float* ctx1   = probs2 + NN;    // [8192,1024]
  float* probs1 = ctx1 + MD;      // [8192,8192]

  const float scale = 1.0f / 32.0f;   // 1/sqrt(1024)

  // casts
  {
    int n4 = (int)(MD / 4);
    int blks = (n4 + 255) / 256;
    cast_f32_bf16<<<blks, 256, 0, stream>>>(x1, x1b, n4);
    cast_f32_bf16<<<blks, 256, 0, stream>>>(x2, x2b, n4);
  }
  {
    int blks = (DIM / 32) * (DIM / 32);
    for (int i = 0; i < 6; ++i)
      transpose_cast32<<<blks, 256, 0, stream>>>(W[i], Wt + i * DD, DIM, DIM);
  }

  // projections: M=8192, N=1024, K=1024  -> grid 64*8 = 512 blocks
  const int gp = (NTOK / 128) * (DIM / 128);
  gemm_nt<0, false><<<gp, 256, 0, stream>>>(x1b, Wt + 0 * DD, NTOK, DIM, DIM, B[0], 0.f, nullptr, q1);
  gemm_nt<0, false><<<gp, 256, 0, stream>>>(x1b, Wt + 1 * DD, NTOK, DIM, DIM, B[1], 0.f, nullptr, k1);
  gemm_nt<1, false><<<gp, 256, 0, stream>>>(x1b, Wt + 2 * DD, NTOK, DIM, DIM, B[2], 0.f, nullptr, v1T);
  gemm_nt<0, false><<<gp, 256, 0, stream>>>(x2b, Wt + 3 * DD, NTOK, DIM, DIM, B[3], 0.f, nullptr, q2);
  gemm_nt<0, false><<<gp, 256, 0, stream>>>(x2b, Wt + 4 * DD, NTOK, DIM, DIM, B[4], 0.f, nullptr, k2);
  gemm_nt<1, false><<<gp, 256, 0, stream>>>(x2b, Wt + 5 * DD, NTOK, DIM, DIM, B[5], 0.f, nullptr, v2T);

  // attention GEMMs
  const int gs = (NTOK / 128) * (NTOK / 128);   // 4096 blocks

  if (probs_bf16) {
    // direction 1 outputs: probs2 = sigmoid(scale * q1 @ k2^T); ctx2 = probs2 @ v2
    gemm_nt<4, false><<<gs, 256, 0, stream>>>(q1, k2, NTOK, NTOK, DIM, nullptr, scale, probs2, probsb);
    gemm_nt<3, false><<<gp, 256, 0, stream>>>(probsb, v2T, NTOK, DIM, NTOK, nullptr, 0.f, ctx2, nullptr);
    // direction 2: probs1 = sigmoid(scale * q2 @ k1^T); ctx1 = probs1 @ v1
    gemm_nt<4, false><<<gs, 256, 0, stream>>>(q2, k1, NTOK, NTOK, DIM, nullptr, scale, probs1, probsb);
    gemm_nt<3, false><<<gp, 256, 0, stream>>>(probsb, v1T, NTOK, DIM, NTOK, nullptr, 0.f, ctx1, nullptr);
  } else {
    gemm_nt<2, false><<<gs, 256, 0, stream>>>(q1, k2, NTOK, NTOK, DIM, nullptr, scale, probs2, nullptr);
    gemm_nt<3, true ><<<gp, 256, 0, stream>>>(probs2, v2T, NTOK, DIM, NTOK, nullptr, 0.f, ctx2, nullptr);
    gemm_nt<2, false><<<gs, 256, 0, stream>>>(q2, k1, NTOK, NTOK, DIM, nullptr, scale, probs1, nullptr);
    gemm_nt<3, true ><<<gp, 256, 0, stream>>>(probs1, v1T, NTOK, DIM, NTOK, nullptr, 0.f, ctx1, nullptr);
  }
}

// Round 3
// 855.922 us; speedup vs baseline: 1.5468x; 1.4155x over previous
//
#include <hip/hip_runtime.h>
#include <hip/hip_bf16.h>

#define DIM   1024
#define NTOK  8192

using bf16 = __hip_bfloat16;
typedef __attribute__((ext_vector_type(8))) short bf16x8;
typedef __attribute__((ext_vector_type(4))) float f32x4;

__device__ __forceinline__ unsigned short f2b(float x) {
  union { __hip_bfloat16 h; unsigned short u; } cv;
  cv.h = __float2bfloat16(x);
  return cv.u;
}

// ---------------- cast f32 -> bf16 ----------------
__global__ __launch_bounds__(256) void cast_f32_bf16(const float* __restrict__ in,
                                                     bf16* __restrict__ out, int n4) {
  int i = blockIdx.x * 256 + threadIdx.x;
  if (i < n4) {
    const float4 v = ((const float4*)in)[i];
    ushort4 p;
    p.x = f2b(v.x); p.y = f2b(v.y); p.z = f2b(v.z); p.w = f2b(v.w);
    ((ushort4*)out)[i] = p;
  }
}

// ------------- tiled transpose + cast: in[R][C] f32 -> out[C][R] bf16 -------------
__global__ __launch_bounds__(256) void transpose_cast32(const float* __restrict__ in,
                                                        bf16* __restrict__ out, int R, int C) {
  __shared__ float t[32][33];
  const int tilesC = C / 32;
  const int c0 = (blockIdx.x % tilesC) * 32;
  const int r0 = (blockIdx.x / tilesC) * 32;
  const int tx = threadIdx.x & 31, ty = threadIdx.x >> 5;
  #pragma unroll
  for (int i = 0; i < 4; ++i) {
    int r = ty + i * 8;
    t[r][tx] = in[(size_t)(r0 + r) * C + c0 + tx];
  }
  __syncthreads();
  #pragma unroll
  for (int i = 0; i < 4; ++i) {
    int cr = ty + i * 8;
    out[(size_t)(c0 + cr) * R + r0 + tx] = __float2bfloat16(t[tx][cr]);
  }
}

// ---------------- pack 6 bias vectors into one stacked array ----------------
__global__ __launch_bounds__(256) void pack_bias(const float* b0, const float* b1,
                                                 const float* b2, const float* b3,
                                                 const float* b4, const float* b5,
                                                 float* __restrict__ out) {
  int i = blockIdx.x * 256 + threadIdx.x;
  if (i < 6 * DIM) {
    int s = i >> 10, o = i & 1023;
    const float* p = (s == 0) ? b0 : (s == 1) ? b1 : (s == 2) ? b2 : (s == 3) ? b3 : (s == 4) ? b4 : b5;
    out[i] = p[o];
  }
}

// ---------------- ctx = p0 + p1 (split-K reduce) ----------------
__global__ __launch_bounds__(256) void add2_f32(const float* __restrict__ a,
                                                const float* __restrict__ b,
                                                float* __restrict__ o, int n4) {
  int i = blockIdx.x * 256 + threadIdx.x;
  if (i < n4) {
    float4 x = ((const float4*)a)[i];
    float4 y = ((const float4*)b)[i];
    x.x += y.x; x.y += y.y; x.z += y.z; x.w += y.w;
    ((float4*)o)[i] = x;
  }
}

// ================= 256x256 8-phase NT GEMM (T1+T2+T3+T4+T5) =================
// C[M,N] = A[M,K] @ Bt[N,K]^T. BK=64, 512 thr = 8 waves (2M x 4N), wave tile 128x64.
// LDS 2 x (A 256x64 + B 256x64) bf16 = 128 KiB, XOR-swizzled col16 ^= row&7
// (realized by pre-swizzled GLOBAL source; LDS dest linear for global_load_lds).
// Phase schedule per K-tile t (cur = t&1):
//   P1 (mh0,k0): read b0+a  | stage B rows128-255 of t+1 -> buf^1
//   P2 (mh0,k1): read b1+a  | stage A rows 64-127,192-255 of t+1 -> buf^1
//   P3 (mh1,k0): read a     | stage A rows 0-63,128-191 of t+2 -> buf
//   P4 (mh1,k1): read a     | stage B rows 0-63,64-127  of t+2 -> buf, vmcnt(4)
// Each phase: reads/stages -> s_barrier -> lgkmcnt(0)+sched_barrier -> 16 MFMA -> s_barrier.
// EPI: 2 = sigmoid->f32 | 3 = f32 (+z*M*N split-K partial) | 4 = sigmoid->f32+bf16
//      5 = fused QKV projection (dual-input: bm >= M/2 selects second set)
template<int EPI>
__global__ __launch_bounds__(512, 2) void gemm256(
    const bf16* __restrict__ A, const bf16* __restrict__ Bt, const bf16* __restrict__ Bt2,
    int M, int N, int K, int tilesN, int ks,
    const float* __restrict__ bias, const float* __restrict__ bias2, float scale,
    float* __restrict__ Cf, bf16* __restrict__ Cb,
    bf16* __restrict__ Cq, bf16* __restrict__ Ck, bf16* __restrict__ Cv,
    bf16* __restrict__ Cq2, bf16* __restrict__ Ck2, bf16* __restrict__ Cv2)
{
  __shared__ bf16 lds[2][2 * 16384];
  const int t    = threadIdx.x;
  const int lane = t & 63, wid = t >> 6;
  const int wr = wid >> 2, wc = wid & 3;
  const int lr = lane & 15, kg = lane >> 4;

  // XCD-aware bijective swizzle (all grids are multiples of 8)
  const int nwg = gridDim.x;
  int bid = blockIdx.x;
  { const int q = nwg >> 3; bid = (bid & 7) * q + (bid >> 3); }
  const int per = nwg / ks;
  const int z   = bid / per;
  const int rem = bid % per;
  const int bm  = (rem / tilesN) << 8;
  const int bn  = (rem % tilesN) << 8;
  const int Kc  = K / ks;
  const int NT  = Kc >> 6;
  const size_t kb = (size_t)z * Kc;

  // dual-input select for fused projection
  const bf16* BtU = Bt;
  const float* biasU = bias;
  bf16 *CqU = Cq, *CkU = Ck, *CvU = Cv;
  int bmL = bm;
  if (EPI == 5 && bm >= (M >> 1)) {
    BtU = Bt2; biasU = bias2; CqU = Cq2; CkU = Ck2; CvU = Cv2; bmL = bm - (M >> 1);
  }

  // staging coords: thread t covers LDS chunk t (16B) of each 8KB region issue.
  // row-in-region = t>>3; global col pre-swizzled so swizzled ds_read sees linear data.
  const int srow = t >> 3;
  const int scol = ((t & 7) ^ (srow & 7)) * 8;
  const size_t bA = (size_t)(bm + srow) * K + kb + scol;
  const size_t bB = (size_t)(bn + srow) * K + kb + scol;

#define STAGE(buf, isB, R0, tt_) do {                                                   \
    const bf16* g_ = ((isB) ? BtU + bB : A + bA) + (size_t)(R0) * K + (size_t)(tt_) * 64; \
    __builtin_amdgcn_global_load_lds(                                                   \
        (const __attribute__((address_space(1))) unsigned int*)g_,                      \
        (__attribute__((address_space(3))) unsigned int*)(&lds[buf][((isB) ? 16384 : 0) + (R0) * 64 + t * 8]), \
        16, 0, 0);                                                                      \
  } while (0)

  // fragment read column offsets (swizzled): col16 = (kk*4+kg) ^ (lr&7)
  const int fcol0 = ((kg)     ^ (lr & 7)) * 8;
  const int fcol1 = ((4 + kg) ^ (lr & 7)) * 8;
  const int arow = (wr * 128 + lr) * 64;   // + (mh*64+mi*16)*64 + fcol
  const int brow = (wc * 64 + lr) * 64;    // + (n*16)*64 + fcol

  f32x4 acc[8][4] = {};

  // ---- prologue: tile0 full (8 regions) -> buf0; tile1 A1,A2,B1,B2 -> buf1 ----
  STAGE(0, false, 0, 0);   STAGE(0, false, 128, 0);
  STAGE(0, false, 64, 0);  STAGE(0, false, 192, 0);
  STAGE(0, true, 0, 0);    STAGE(0, true, 64, 0);
  STAGE(0, true, 128, 0);  STAGE(0, true, 192, 0);
  if (NT > 1) {
    STAGE(1, false, 0, 1); STAGE(1, false, 128, 1);
    STAGE(1, true, 0, 1);  STAGE(1, true, 64, 1);
    asm volatile("s_waitcnt vmcnt(4)" ::: "memory");
  } else {
    asm volatile("s_waitcnt vmcnt(0)" ::: "memory");
  }
  __builtin_amdgcn_sched_barrier(0);
  __builtin_amdgcn_s_barrier();

  for (int tt = 0; tt < NT; ++tt) {
    const int cur = tt & 1;
    const bf16* bufA = &lds[cur][0];
    const bf16* bufB = &lds[cur][16384];
    bf16x8 b0[4], b1[4];

    // -------- P1: mh=0, kk=0 --------
    {
      bf16x8 a[4];
      #pragma unroll
      for (int n = 0; n < 4; ++n) b0[n] = *(const bf16x8*)(bufB + brow + n * 1024 + fcol0);
      #pragma unroll
      for (int mi = 0; mi < 4; ++mi) a[mi] = *(const bf16x8*)(bufA + arow + mi * 1024 + fcol0);
      if (tt + 1 < NT) { STAGE(cur ^ 1, true, 128, tt + 1); STAGE(cur ^ 1, true, 192, tt + 1); }
      __builtin_amdgcn_s_barrier();
      asm volatile("s_waitcnt lgkmcnt(0)" ::: "memory");
      __builtin_amdgcn_sched_barrier(0);
      __builtin_amdgcn_s_setprio(1);
      #pragma unroll
      for (int mi = 0; mi < 4; ++mi)
        #pragma unroll
        for (int n = 0; n < 4; ++n)
          acc[mi][n] = __builtin_amdgcn_mfma_f32_16x16x32_bf16(a[mi], b0[n], acc[mi][n], 0, 0, 0);
      __builtin_amdgcn_s_setprio(0);
      __builtin_amdgcn_s_barrier();
    }
    // -------- P2: mh=0, kk=1 --------
    {
      bf16x8 a[4];
      #pragma unroll
      for (int n = 0; n < 4; ++n) b1[n] = *(const bf16x8*)(bufB + brow + n * 1024 + fcol1);
      #pragma unroll
      for (int mi = 0; mi < 4; ++mi) a[mi] = *(const bf16x8*)(bufA + arow + mi * 1024 + fcol1);
      if (tt + 1 < NT) { STAGE(cur ^ 1, false, 64, tt + 1); STAGE(cur ^ 1, false, 192, tt + 1); }
      __builtin_amdgcn_s_barrier();
      asm volatile("s_waitcnt lgkmcnt(0)" ::: "memory");
      __builtin_amdgcn_sched_barrier(0);
      __builtin_amdgcn_s_setprio(1);
      #pragma unroll
      for (int mi = 0; mi < 4; ++mi)
        #pragma unroll
        for (int n = 0; n < 4; ++n)
          acc[mi][n] = __builtin_amdgcn_mfma_f32_16x16x32_bf16(a[mi], b1[n], acc[mi][n], 0, 0, 0);
      __builtin_amdgcn_s_setprio(0);
      __builtin_amdgcn_s_barrier();
    }
    // -------- P3: mh=1, kk=0 --------
    {
      bf16x8 a[4];
      #pragma unroll
      for (int mi = 0; mi < 4; ++mi) a[mi] = *(const bf16x8*)(bufA + arow + 4096 + mi * 1024 + fcol0);
      if (tt + 2 < NT) { STAGE(cur, false, 0, tt + 2); STAGE(cur, false, 128, tt + 2); }
      __builtin_amdgcn_s_barrier();
      asm volatile("s_waitcnt lgkmcnt(0)" ::: "memory");
      __builtin_amdgcn_sched_barrier(0);
      __builtin_amdgcn_s_setprio(1);
      #pragma unroll
      for (int mi = 0; mi < 4; ++mi)
        #pragma unroll
        for (int n = 0; n < 4; ++n)
          acc[4 + mi][n] = __builtin_amdgcn_mfma_f32_16x16x32_bf16(a[mi], b0[n], acc[4 + mi][n], 0, 0, 0);
      __builtin_amdgcn_s_setprio(0);
      __builtin_amdgcn_s_barrier();
    }
    // -------- P4: mh=1, kk=1 --------
    {
      bf16x8 a[4];
      #pragma unroll
      for (int mi = 0; mi < 4; ++mi) a[mi] = *(const bf16x8*)(bufA + arow + 4096 + mi * 1024 + fcol1);
      if (tt + 2 < NT) { STAGE(cur, true, 0, tt + 2); STAGE(cur, true, 64, tt + 2); }
      __builtin_amdgcn_s_barrier();
      asm volatile("s_waitcnt lgkmcnt(0)" ::: "memory");
      __builtin_amdgcn_sched_barrier(0);
      __builtin_amdgcn_s_setprio(1);
      #pragma unroll
      for (int mi = 0; mi < 4; ++mi)
        #pragma unroll
        for (int n = 0; n < 4; ++n)
          acc[4 + mi][n] = __builtin_amdgcn_mfma_f32_16x16x32_bf16(a[mi], b1[n], acc[4 + mi][n], 0, 0, 0);
      __builtin_amdgcn_s_setprio(0);
      if (tt + 2 < NT) { asm volatile("s_waitcnt vmcnt(4)" ::: "memory"); }
      else             { asm volatile("s_waitcnt vmcnt(0)" ::: "memory"); }
      __builtin_amdgcn_sched_barrier(0);
      __builtin_amdgcn_s_barrier();
    }
  }
#undef STAGE

  // ---- epilogue ----
  const int er = wr * 128 + kg * 4;        // + m*16 + e (local row)
  const int ec = bn + wc * 64 + lr;        // + n*16 (global col)

  if (EPI == 2 || EPI == 4) {
    #pragma unroll
    for (int m = 0; m < 8; ++m) {
      #pragma unroll
      for (int n = 0; n < 4; ++n) {
        const int c = ec + n * 16;
        #pragma unroll
        for (int e = 0; e < 4; ++e) {
          const size_t idx = (size_t)(bm + er + m * 16 + e) * N + c;
          float pr = 1.0f / (1.0f + __expf(-acc[m][n][e] * scale));
          Cf[idx] = pr;
          if (EPI == 4) Cb[idx] = __float2bfloat16(pr);
        }
      }
    }
  } else if (EPI == 3) {
    float* Cz = Cf + (size_t)z * ((size_t)M * N);
    #pragma unroll
    for (int m = 0; m < 8; ++m)
      #pragma unroll
      for (int n = 0; n < 4; ++n)
        #pragma unroll
        for (int e = 0; e < 4; ++e)
          Cz[(size_t)(bm + er + m * 16 + e) * N + ec + n * 16] = acc[m][n][e];
  } else if (EPI == 5) {
    const int seg = bn >> 10;              // 0=q 1=k 2=v (block-uniform; 256|1024)
    #pragma unroll
    for (int m = 0; m < 8; ++m) {
      #pragma unroll
      for (int n = 0; n < 4; ++n) {
        const int c  = ec + n * 16;
        const int cl = c & 1023;
        const float b = biasU[c];
        #pragma unroll
        for (int e = 0; e < 4; ++e) {
          const int r = bmL + er + m * 16 + e;
          const float val = acc[m][n][e] + b;
          if (seg == 0)      CqU[(size_t)r * DIM + cl] = __float2bfloat16(val);
          else if (seg == 1) CkU[(size_t)r * DIM + cl] = __float2bfloat16(val);
          else               CvU[(size_t)cl * NTOK + r] = __float2bfloat16(val);
        }
      }
    }
  }
}

// ================= legacy 128x128 GEMM (tier-C fallback only) =================
template<int EPI, bool A_F32>
__global__ __launch_bounds__(256) void gemm_nt(
    const void* __restrict__ Ap, const bf16* __restrict__ Bt,
    int M, int N, int K,
    const float* __restrict__ bias, float scale,
    float* __restrict__ Cf, bf16* __restrict__ Cb)
{
  __shared__ bf16 As[128 * 32];
  __shared__ bf16 Bs[128 * 32];
  const int tid  = threadIdx.x;
  const int lane = tid & 63, wid = tid >> 6;
  const int wr = wid >> 1, wc = wid & 1;
  const int tilesN = N >> 7;
  const int nwg = gridDim.x;
  int bid = blockIdx.x;
  if ((nwg & 7) == 0) { const int q = nwg >> 3; bid = (bid & 7) * q + (bid >> 3); }
  const int bm = (bid / tilesN) * 128, bn = (bid % tilesN) * 128;
  f32x4 acc[4][4] = {};
  const bf16*  Ab16 = (const bf16*)Ap;
  const float* Af32 = (const float*)Ap;
  const int srow = tid >> 2, sc8 = (tid & 3) * 8;
  const int frow = tid >> 3, fc4 = (tid & 7) * 4;

  for (int k0 = 0; k0 < K; k0 += 32) {
    if (A_F32) {
      #pragma unroll
      for (int is = 0; is < 4; ++is) {
        int row = is * 32 + frow;
        const float4 v = *(const float4*)(Af32 + (size_t)(bm + row) * K + k0 + fc4);
        ushort4 p; p.x = f2b(v.x); p.y = f2b(v.y); p.z = f2b(v.z); p.w = f2b(v.w);
        *(ushort4*)(&As[row * 32 + fc4]) = p;
      }
    } else {
      #pragma unroll
      for (int is = 0; is < 2; ++is) {
        int row = is * 64 + srow;
        const bf16* g = Ab16 + (size_t)(bm + row) * K + k0 + sc8;
        __builtin_amdgcn_global_load_lds(
            (const __attribute__((address_space(1))) unsigned int*)g,
            (__attribute__((address_space(3))) unsigned int*)(&As[row * 32 + sc8]), 16, 0, 0);
      }
    }
    #pragma unroll
    for (int is = 0; is < 2; ++is) {
      int row = is * 64 + srow;
      const bf16* g = Bt + (size_t)(bn + row) * K + k0 + sc8;
      __builtin_amdgcn_global_load_lds(
          (const __attribute__((address_space(1))) unsigned int*)g,
          (__attribute__((address_space(3))) unsigned int*)(&Bs[row * 32 + sc8]), 16, 0, 0);
    }
    __syncthreads();
    const int lr = lane & 15, kg = lane >> 4;
    bf16x8 af[4], bfv[4];
    #pragma unroll
    for (int i = 0; i < 4; ++i)
      af[i] = *(const bf16x8*)(&As[(wr * 64 + i * 16 + lr) * 32 + kg * 8]);
    #pragma unroll
    for (int j = 0; j < 4; ++j)
      bfv[j] = *(const bf16x8*)(&Bs[(wc * 64 + j * 16 + lr) * 32 + kg * 8]);
    #pragma unroll
    for (int i = 0; i < 4; ++i)
      #pragma unroll
      for (int j = 0; j < 4; ++j)
        acc[i][j] = __builtin_amdgcn_mfma_f32_16x16x32_bf16(af[i], bfv[j], acc[i][j], 0, 0, 0);
    __syncthreads();
  }
  const int r0 = bm + wr * 64 + (lane >> 4) * 4;
  const int c0 = bn + wc * 64 + (lane & 15);
  if (EPI == 2) {
    #pragma unroll
    for (int i = 0; i < 4; ++i)
      #pragma unroll
      for (int j = 0; j < 4; ++j)
        #pragma unroll
        for (int e = 0; e < 4; ++e) {
          float pr = 1.0f / (1.0f + __expf(-acc[i][j][e] * scale));
          Cf[(size_t)(r0 + i * 16 + e) * N + c0 + j * 16] = pr;
        }
  } else {
    #pragma unroll
    for (int i = 0; i < 4; ++i)
      #pragma unroll
      for (int j = 0; j < 4; ++j)
        #pragma unroll
        for (int e = 0; e < 4; ++e)
          Cf[(size_t)(r0 + i * 16 + e) * N + c0 + j * 16] = acc[i][j][e];
  }
}

extern "C" void kernel_launch(void* const* d_in, const int* in_sizes, int n_in,
                              void* d_out, int out_size, void* d_ws, size_t ws_size,
                              hipStream_t stream) {
  const float* x1 = (const float*)d_in[0];
  const float* x2 = (const float*)d_in[1];
  const float* W[6] = { (const float*)d_in[2],  (const float*)d_in[4],  (const float*)d_in[6],
                        (const float*)d_in[8],  (const float*)d_in[10], (const float*)d_in[12] };
  const float* B[6] = { (const float*)d_in[3],  (const float*)d_in[5],  (const float*)d_in[7],
                        (const float*)d_in[9],  (const float*)d_in[11], (const float*)d_in[13] };

  const size_t MD = (size_t)NTOK * DIM;   // 8,388,608
  const size_t DD = (size_t)DIM * DIM;    // 1,048,576
  const size_t NN = (size_t)NTOK * NTOK;  // 67,108,864

  // ws layout (bf16 elements)
  bf16* ws   = (bf16*)d_ws;
  bf16* x1b  = ws;                    // 8M  (x1b/x2b contiguous -> fused proj A)
  bf16* x2b  = x1b + MD;              // 8M
  bf16* wt1  = x2b + MD;              // 3M  [Wq1T;Wk1T;Wv1T]
  bf16* wt2  = wt1 + 3 * DD;          // 3M
  float* bstack = (float*)(wt2 + 3 * DD);  // 6144 f32 (in 16384 bf16 slot)
  bf16* q1   = wt2 + 3 * DD + 16384;
  bf16* k1   = q1 + MD;
  bf16* v1T  = k1 + MD;
  bf16* q2   = v1T + MD;
  bf16* k2   = q2 + MD;
  bf16* v2T  = k2 + MD;
  bf16* probsb = v2T + MD;            // 64M bf16
  float* part  = (float*)(probsb + NN);  // 2 x 8M f32

  const size_t baseB  = (size_t)((8 * MD) + 6 * DD + 16384) * 2;  // ~147 MB
  const size_t tierBB = baseB + NN * 2;                           // ~281 MB
  const size_t tierAB = tierBB + 2 * MD * 4;                      // ~348 MB
  const bool hasProbsB = (ws_size >= tierBB);
  const bool hasSplitK = (ws_size >= tierAB);

  float* out    = (float*)d_out;
  float* ctx2   = out;
  float* probs2 = ctx2 + MD;
  float* ctx1   = probs2 + NN;
  float* probs1 = ctx1 + MD;

  const float scale = 1.0f / 32.0f;

  // casts + weight transposes + bias pack
  {
    int n4 = (int)(MD / 4);
    int blks = (n4 + 255) / 256;
    cast_f32_bf16<<<blks, 256, 0, stream>>>(x1, x1b, n4);
    cast_f32_bf16<<<blks, 256, 0, stream>>>(x2, x2b, n4);
  }
  {
    int blks = (DIM / 32) * (DIM / 32);
    transpose_cast32<<<blks, 256, 0, stream>>>(W[0], wt1 + 0 * DD, DIM, DIM);
    transpose_cast32<<<blks, 256, 0, stream>>>(W[1], wt1 + 1 * DD, DIM, DIM);
    transpose_cast32<<<blks, 256, 0, stream>>>(W[2], wt1 + 2 * DD, DIM, DIM);
    transpose_cast32<<<blks, 256, 0, stream>>>(W[3], wt2 + 0 * DD, DIM, DIM);
    transpose_cast32<<<blks, 256, 0, stream>>>(W[4], wt2 + 1 * DD, DIM, DIM);
    transpose_cast32<<<blks, 256, 0, stream>>>(W[5], wt2 + 2 * DD, DIM, DIM);
  }
  pack_bias<<<24, 256, 0, stream>>>(B[0], B[1], B[2], B[3], B[4], B[5], bstack);

  // fused QKV projection: A = [x1b; x2b] (16384 x 1024), Bt selected per half.
  // grid = 64 M-tiles x 12 N-tiles = 768 blocks.
  gemm256<5><<<64 * 12, 512, 0, stream>>>(
      x1b, wt1, wt2, 2 * NTOK, 3 * DIM, DIM, 12, 1,
      bstack, bstack + 3 * DIM, 0.f,
      nullptr, nullptr, q1, k1, v1T, q2, k2, v2T);

  const int gQK = (NTOK / 256) * (NTOK / 256);   // 1024
  const int gPV1 = (NTOK / 256) * (DIM / 256);   // 128

  if (hasProbsB) {
    // probs2 = sigmoid(scale * q1 @ k2^T)  -> f32 (out) + bf16 (ws)
    gemm256<4><<<gQK, 512, 0, stream>>>(q1, k2, nullptr, NTOK, NTOK, DIM, 32, 1,
        nullptr, nullptr, scale, probs2, probsb,
        nullptr, nullptr, nullptr, nullptr, nullptr, nullptr);
    if (hasSplitK) {
      gemm256<3><<<2 * gPV1, 512, 0, stream>>>(probsb, v2T, nullptr, NTOK, DIM, NTOK, 4, 2,
          nullptr, nullptr, 0.f, part, nullptr,
          nullptr, nullptr, nullptr, nullptr, nullptr, nullptr);
      add2_f32<<<(int)(MD / 4 + 255) / 256, 256, 0, stream>>>(part, part + MD, ctx2, (int)(MD / 4));
    } else {
      gemm256<3><<<gPV1, 512, 0, stream>>>(probsb, v2T, nullptr, NTOK, DIM, NTOK, 4, 1,
          nullptr, nullptr, 0.f, ctx2, nullptr,
          nullptr, nullptr, nullptr, nullptr, nullptr, nullptr);
    }
    // probs1 = sigmoid(scale * q2 @ k1^T)
    gemm256<4><<<gQK, 512, 0, stream>>>(q2, k1, nullptr, NTOK, NTOK, DIM, 32, 1,
        nullptr, nullptr, scale, probs1, probsb,
        nullptr, nullptr, nullptr, nullptr, nullptr, nullptr);
    if (hasSplitK) {
      gemm256<3><<<2 * gPV1, 512, 0, stream>>>(probsb, v1T, nullptr, NTOK, DIM, NTOK, 4, 2,
          nullptr, nullptr, 0.f, part, nullptr,
          nullptr, nullptr, nullptr, nullptr, nullptr, nullptr);
      add2_f32<<<(int)(MD / 4 + 255) / 256, 256, 0, stream>>>(part, part + MD, ctx1, (int)(MD / 4));
    } else {
      gemm256<3><<<gPV1, 512, 0, stream>>>(probsb, v1T, nullptr, NTOK, DIM, NTOK, 4, 1,
          nullptr, nullptr, 0.f, ctx1, nullptr,
          nullptr, nullptr, nullptr, nullptr, nullptr, nullptr);
    }
  } else {
    // tier C: probs f32 only; PV re-reads f32 probs with convert-on-stage
    const int gs = (NTOK / 128) * (NTOK / 128);
    const int gp = (NTOK / 128) * (DIM / 128);
    gemm_nt<2, false><<<gs, 256, 0, stream>>>(q1, k2, NTOK, NTOK, DIM, nullptr, scale, probs2, nullptr);
    gemm_nt<3, true ><<<gp, 256, 0, stream>>>(probs2, v2T, NTOK, DIM, NTOK, nullptr, 0.f, ctx2, nullptr);
    gemm_nt<2, false><<<gs, 256, 0, stream>>>(q2, k1, NTOK, NTOK, DIM, nullptr, scale, probs1, nullptr);
    gemm_nt<3, true ><<<gp, 256, 0, stream>>>(probs1, v1T, NTOK, DIM, NTOK, nullptr, 0.f, ctx1, nullptr);
  }
}

// Round 4
// 831.560 us; speedup vs baseline: 1.5921x; 1.0293x over previous
//
#include <hip/hip_runtime.h>
#include <hip/hip_bf16.h>

#define DIM   1024
#define NTOK  8192

using bf16 = __hip_bfloat16;
typedef __attribute__((ext_vector_type(8))) short bf16x8;
typedef __attribute__((ext_vector_type(4))) float f32x4;

__device__ __forceinline__ unsigned short f2b(float x) {
  union { __hip_bfloat16 h; unsigned short u; } cv;
  cv.h = __float2bfloat16(x);
  return cv.u;
}

// ---------------- cast f32 -> bf16 ----------------
__global__ __launch_bounds__(256) void cast_f32_bf16(const float* __restrict__ in,
                                                     bf16* __restrict__ out, int n4) {
  int i = blockIdx.x * 256 + threadIdx.x;
  if (i < n4) {
    const float4 v = ((const float4*)in)[i];
    ushort4 p;
    p.x = f2b(v.x); p.y = f2b(v.y); p.z = f2b(v.z); p.w = f2b(v.w);
    ((ushort4*)out)[i] = p;
  }
}

// ------------- tiled transpose + cast: in[R][C] f32 -> out[C][R] bf16 -------------
__global__ __launch_bounds__(256) void transpose_cast32(const float* __restrict__ in,
                                                        bf16* __restrict__ out, int R, int C) {
  __shared__ float t[32][33];
  const int tilesC = C / 32;
  const int c0 = (blockIdx.x % tilesC) * 32;
  const int r0 = (blockIdx.x / tilesC) * 32;
  const int tx = threadIdx.x & 31, ty = threadIdx.x >> 5;
  #pragma unroll
  for (int i = 0; i < 4; ++i) {
    int r = ty + i * 8;
    t[r][tx] = in[(size_t)(r0 + r) * C + c0 + tx];
  }
  __syncthreads();
  #pragma unroll
  for (int i = 0; i < 4; ++i) {
    int cr = ty + i * 8;
    out[(size_t)(c0 + cr) * R + r0 + tx] = __float2bfloat16(t[tx][cr]);
  }
}

// ------------- bf16 transpose, 64x64 tiles, vectorized both sides, dual-input -------------
// in[R][C] bf16 -> out[C][R] bf16 (and same for in2/out2). Swizzled LDS chunks.
__global__ __launch_bounds__(256) void transpose_bf16(const short* __restrict__ in,
                                                      short* __restrict__ out,
                                                      const short* __restrict__ in2,
                                                      short* __restrict__ out2,
                                                      int R, int C) {
  __shared__ short t[64][72];
  const int tilesC = C >> 6;
  const int tilesPer = (R >> 6) * tilesC;
  int bid = blockIdx.x;
  const short* src = in; short* dst = out;
  if (bid >= tilesPer) { bid -= tilesPer; src = in2; dst = out2; }
  const int r0 = (bid / tilesC) << 6, c0 = (bid % tilesC) << 6;
  const int tr = threadIdx.x >> 3, tc8 = (threadIdx.x & 7) << 3;
  #pragma unroll
  for (int p = 0; p < 2; ++p) {
    int r = tr + p * 32;
    int sc = tc8 ^ (((r >> 3) & 7) << 3);   // swizzle 8-short chunks by row-octet
    *(bf16x8*)&t[r][sc] = *(const bf16x8*)&src[(size_t)(r0 + r) * C + c0 + tc8];
  }
  __syncthreads();
  #pragma unroll
  for (int p = 0; p < 2; ++p) {
    int oc = tr + p * 32;                   // input col = output row
    bf16x8 v;
    #pragma unroll
    for (int e = 0; e < 8; ++e) {
      int a = tc8 + e;                      // input row
      v[e] = t[a][oc ^ (((a >> 3) & 7) << 3)];
    }
    *(bf16x8*)&dst[(size_t)(c0 + oc) * R + r0 + tc8] = v;
  }
}

// ---------------- pack 6 bias vectors ----------------
__global__ __launch_bounds__(256) void pack_bias(const float* b0, const float* b1,
                                                 const float* b2, const float* b3,
                                                 const float* b4, const float* b5,
                                                 float* __restrict__ out) {
  int i = blockIdx.x * 256 + threadIdx.x;
  if (i < 6 * DIM) {
    int s = i >> 10, o = i & 1023;
    const float* p = (s == 0) ? b0 : (s == 1) ? b1 : (s == 2) ? b2 : (s == 3) ? b3 : (s == 4) ? b4 : b5;
    out[i] = p[o];
  }
}

// ---------------- split-K reduce for both directions ----------------
// parts layout: [d0z0][d0z1][d1z0][d1z1], each MD f32. o0 = d0z0+d0z1, o1 = d1z0+d1z1.
__global__ __launch_bounds__(256) void add2_dual(const float* __restrict__ p,
                                                 float* __restrict__ o0,
                                                 float* __restrict__ o1, int n4) {
  const size_t MD = (size_t)NTOK * DIM;
  int i = blockIdx.x * 256 + threadIdx.x;
  if (i < 2 * n4) {
    int d = i >= n4;
    int j = i - d * n4;
    const float4 a = ((const float4*)(p + (size_t)d * 2 * MD))[j];
    const float4 b = ((const float4*)(p + (size_t)d * 2 * MD + MD))[j];
    float4 r; r.x = a.x + b.x; r.y = a.y + b.y; r.z = a.z + b.z; r.w = a.w + b.w;
    ((float4*)(d ? o1 : o0))[j] = r;
  }
}

// ================= 256x256 8-phase NT GEMM (T1+T2+T3+T4+T5) =================
// C[M,N] = A[M,K] @ Bt[N,K]^T. BK=64, 512 thr = 8 waves (2M x 4N), wave tile 128x64.
// DUAL: grid = 2*perDir; second half uses A2/Bt2/Cf2/Cb2 (two independent GEMMs).
// EPI: 2 = sigmoid->f32 | 3 = f32 split-K partial | 4 = sigmoid->f32+bf16
//      5 = fused QKV projection (dual-by-row: bm >= M/2 selects second set; q/k/v ROW-major)
// All epilogues: LDS-transposed, coalesced f32x4 / ushort4 stores.
template<int EPI, bool DUAL>
__global__ __launch_bounds__(512, 2) void gemm256(
    const bf16* __restrict__ A,  const bf16* __restrict__ Bt,
    const bf16* __restrict__ A2, const bf16* __restrict__ Bt2,
    int M, int N, int K, int tilesN, int ks, int perDir,
    const float* __restrict__ bias, const float* __restrict__ bias2, float scale,
    float* __restrict__ Cf, float* __restrict__ Cf2,
    bf16* __restrict__ Cb, bf16* __restrict__ Cb2,
    bf16* __restrict__ Cq, bf16* __restrict__ Ck, bf16* __restrict__ Cv,
    bf16* __restrict__ Cq2, bf16* __restrict__ Ck2, bf16* __restrict__ Cv2)
{
  __shared__ bf16 lds[2][2 * 16384];
  const int t    = threadIdx.x;
  const int lane = t & 63, wid = t >> 6;
  const int wr = wid >> 2, wc = wid & 3;
  const int lr = lane & 15, kg = lane >> 4;

  // XCD-aware bijective swizzle (all grids are multiples of 8)
  const int nwg = gridDim.x;
  int bid = blockIdx.x;
  { const int q = nwg >> 3; bid = (bid & 7) * q + (bid >> 3); }

  // direction select (DUAL) + split-K decompose
  const bf16* Au = A; const bf16* BtU = Bt;
  float* CfU = Cf; bf16* CbU = Cb;
  int bidL = bid;
  if (DUAL && bidL >= perDir) { bidL -= perDir; Au = A2; BtU = Bt2; CfU = Cf2; CbU = Cb2; }
  const int per = perDir / ks;
  const int z   = bidL / per;
  const int rem = bidL % per;
  const int bm  = (rem / tilesN) << 8;
  const int bn  = (rem % tilesN) << 8;
  const int Kc  = K / ks;
  const int NT  = Kc >> 6;
  const size_t kb = (size_t)z * Kc;

  // proj: dual-by-row select
  const float* biasU = bias;
  bf16 *CqU = Cq, *CkU = Ck, *CvU = Cv;
  int bmL = bm;
  if (EPI == 5 && bm >= (M >> 1)) {
    BtU = Bt2; biasU = bias2; CqU = Cq2; CkU = Ck2; CvU = Cv2; bmL = bm - (M >> 1);
  }

  // staging: thread t covers one 16B chunk of each 64-row region; source col pre-swizzled
  const int srow = t >> 3;
  const int scol = ((t & 7) ^ (srow & 7)) * 8;
  const size_t bA = (size_t)(bm + srow) * K + kb + scol;
  const size_t bB = (size_t)(bn + srow) * K + kb + scol;

#define STAGE(buf, isB, R0, tt_) do {                                                   \
    const bf16* g_ = ((isB) ? BtU + bB : Au + bA) + (size_t)(R0) * K + (size_t)(tt_) * 64; \
    __builtin_amdgcn_global_load_lds(                                                   \
        (const __attribute__((address_space(1))) unsigned int*)g_,                      \
        (__attribute__((address_space(3))) unsigned int*)(&lds[buf][((isB) ? 16384 : 0) + (R0) * 64 + t * 8]), \
        16, 0, 0);                                                                      \
  } while (0)

  // fragment read offsets (swizzled): col16 = (kk*4+kg) ^ (lr&7)
  const int fcol0 = ((kg)     ^ (lr & 7)) * 8;
  const int fcol1 = ((4 + kg) ^ (lr & 7)) * 8;
  const int arow = (wr * 128 + lr) * 64;
  const int brow = (wc * 64 + lr) * 64;

  f32x4 acc[8][4] = {};

  // ---- prologue ----
  STAGE(0, false, 0, 0);   STAGE(0, false, 128, 0);
  STAGE(0, false, 64, 0);  STAGE(0, false, 192, 0);
  STAGE(0, true, 0, 0);    STAGE(0, true, 64, 0);
  STAGE(0, true, 128, 0);  STAGE(0, true, 192, 0);
  if (NT > 1) {
    STAGE(1, false, 0, 1); STAGE(1, false, 128, 1);
    STAGE(1, true, 0, 1);  STAGE(1, true, 64, 1);
    asm volatile("s_waitcnt vmcnt(4)" ::: "memory");
  } else {
    asm volatile("s_waitcnt vmcnt(0)" ::: "memory");
  }
  __builtin_amdgcn_sched_barrier(0);
  __builtin_amdgcn_s_barrier();

  for (int tt = 0; tt < NT; ++tt) {
    const int cur = tt & 1;
    const bf16* bufA = &lds[cur][0];
    const bf16* bufB = &lds[cur][16384];
    bf16x8 b0[4], b1[4];

    { // P1: mh=0, kk=0
      bf16x8 a[4];
      #pragma unroll
      for (int n = 0; n < 4; ++n) b0[n] = *(const bf16x8*)(bufB + brow + n * 1024 + fcol0);
      #pragma unroll
      for (int mi = 0; mi < 4; ++mi) a[mi] = *(const bf16x8*)(bufA + arow + mi * 1024 + fcol0);
      if (tt + 1 < NT) { STAGE(cur ^ 1, true, 128, tt + 1); STAGE(cur ^ 1, true, 192, tt + 1); }
      __builtin_amdgcn_s_barrier();
      asm volatile("s_waitcnt lgkmcnt(0)" ::: "memory");
      __builtin_amdgcn_sched_barrier(0);
      __builtin_amdgcn_s_setprio(1);
      #pragma unroll
      for (int mi = 0; mi < 4; ++mi)
        #pragma unroll
        for (int n = 0; n < 4; ++n)
          acc[mi][n] = __builtin_amdgcn_mfma_f32_16x16x32_bf16(a[mi], b0[n], acc[mi][n], 0, 0, 0);
      __builtin_amdgcn_s_setprio(0);
      __builtin_amdgcn_s_barrier();
    }
    { // P2: mh=0, kk=1
      bf16x8 a[4];
      #pragma unroll
      for (int n = 0; n < 4; ++n) b1[n] = *(const bf16x8*)(bufB + brow + n * 1024 + fcol1);
      #pragma unroll
      for (int mi = 0; mi < 4; ++mi) a[mi] = *(const bf16x8*)(bufA + arow + mi * 1024 + fcol1);
      if (tt + 1 < NT) { STAGE(cur ^ 1, false, 64, tt + 1); STAGE(cur ^ 1, false, 192, tt + 1); }
      __builtin_amdgcn_s_barrier();
      asm volatile("s_waitcnt lgkmcnt(0)" ::: "memory");
      __builtin_amdgcn_sched_barrier(0);
      __builtin_amdgcn_s_setprio(1);
      #pragma unroll
      for (int mi = 0; mi < 4; ++mi)
        #pragma unroll
        for (int n = 0; n < 4; ++n)
          acc[mi][n] = __builtin_amdgcn_mfma_f32_16x16x32_bf16(a[mi], b1[n], acc[mi][n], 0, 0, 0);
      __builtin_amdgcn_s_setprio(0);
      __builtin_amdgcn_s_barrier();
    }
    { // P3: mh=1, kk=0
      bf16x8 a[4];
      #pragma unroll
      for (int mi = 0; mi < 4; ++mi) a[mi] = *(const bf16x8*)(bufA + arow + 4096 + mi * 1024 + fcol0);
      if (tt + 2 < NT) { STAGE(cur, false, 0, tt + 2); STAGE(cur, false, 128, tt + 2); }
      __builtin_amdgcn_s_barrier();
      asm volatile("s_waitcnt lgkmcnt(0)" ::: "memory");
      __builtin_amdgcn_sched_barrier(0);
      __builtin_amdgcn_s_setprio(1);
      #pragma unroll
      for (int mi = 0; mi < 4; ++mi)
        #pragma unroll
        for (int n = 0; n < 4; ++n)
          acc[4 + mi][n] = __builtin_amdgcn_mfma_f32_16x16x32_bf16(a[mi], b0[n], acc[4 + mi][n], 0, 0, 0);
      __builtin_amdgcn_s_setprio(0);
      __builtin_amdgcn_s_barrier();
    }
    { // P4: mh=1, kk=1
      bf16x8 a[4];
      #pragma unroll
      for (int mi = 0; mi < 4; ++mi) a[mi] = *(const bf16x8*)(bufA + arow + 4096 + mi * 1024 + fcol1);
      if (tt + 2 < NT) { STAGE(cur, true, 0, tt + 2); STAGE(cur, true, 64, tt + 2); }
      __builtin_amdgcn_s_barrier();
      asm volatile("s_waitcnt lgkmcnt(0)" ::: "memory");
      __builtin_amdgcn_sched_barrier(0);
      __builtin_amdgcn_s_setprio(1);
      #pragma unroll
      for (int mi = 0; mi < 4; ++mi)
        #pragma unroll
        for (int n = 0; n < 4; ++n)
          acc[4 + mi][n] = __builtin_amdgcn_mfma_f32_16x16x32_bf16(a[mi], b1[n], acc[4 + mi][n], 0, 0, 0);
      __builtin_amdgcn_s_setprio(0);
      if (tt + 2 < NT) { asm volatile("s_waitcnt vmcnt(4)" ::: "memory"); }
      else             { asm volatile("s_waitcnt vmcnt(0)" ::: "memory"); }
      __builtin_amdgcn_sched_barrier(0);
      __builtin_amdgcn_s_barrier();
    }
  }
#undef STAGE

  // ======== LDS-transposed epilogue: coalesced stores ========
  // acc[m][n][e]: global row = bm + wr*128 + kg*4 + m*16 + e, col = bn + wc*64 + n*16 + lr.
  // Per half h (=wr): stage 128x256 f32 in LDS (xor-swizzled), read back row-major,
  // store f32x4 (16B/lane) and/or ushort4 bf16 (8B/lane).
  float* Lf = (float*)&lds[0][0];   // 32768 f32 = 128 KiB

  float bN[4];
  if (EPI == 5) {
    #pragma unroll
    for (int n = 0; n < 4; ++n) bN[n] = biasU[bn + wc * 64 + n * 16 + lr];
  }

  #pragma unroll
  for (int h = 0; h < 2; ++h) {
    if (wr == h) {
      #pragma unroll
      for (int m = 0; m < 8; ++m)
        #pragma unroll
        for (int n = 0; n < 4; ++n)
          #pragma unroll
          for (int e = 0; e < 4; ++e) {
            const int lrow = kg * 4 + m * 16 + e;          // 0..127
            const int lcol = wc * 64 + n * 16 + lr;        // 0..255
            float v = acc[m][n][e];
            if (EPI == 2 || EPI == 4) v = 1.0f / (1.0f + __expf(-v * scale));
            if (EPI == 5) v += bN[n];
            Lf[lrow * 256 + (lcol ^ (((lrow >> 2) & 3) << 4))] = v;
          }
    }
    __syncthreads();
    #pragma unroll
    for (int rr = 0; rr < 2; ++rr) {
      const int lrow = wid * 16 + rr * 8 + (lane >> 3);    // 8 rows per wave per pass? no:
      // each wave handles 16 rows; process 2 rows per iteration set below
      (void)lrow;
    }
    // wave wid handles rows [wid*16, wid*16+16)
    #pragma unroll
    for (int rr = 0; rr < 16; ++rr) {
      const int lrow = wid * 16 + rr;
      const int cb   = lane * 4;                            // 0..252
      const int cbs  = cb ^ (((lrow >> 2) & 3) << 4);
      const f32x4 v  = *(const f32x4*)&Lf[lrow * 256 + cbs];
      const int gr   = bm + h * 128 + lrow;
      const int gc   = bn + cb;
      if (EPI == 2 || EPI == 4) {
        *(f32x4*)&CfU[(size_t)gr * N + gc] = v;
        if (EPI == 4) {
          ushort4 p; p.x = f2b(v[0]); p.y = f2b(v[1]); p.z = f2b(v[2]); p.w = f2b(v[3]);
          *(ushort4*)&CbU[(size_t)gr * N + gc] = p;
        }
      } else if (EPI == 3) {
        float* Cz = CfU + (size_t)z * ((size_t)M * N);
        *(f32x4*)&Cz[(size_t)gr * N + gc] = v;
      } else if (EPI == 5) {
        const int seg = bn >> 10;                           // block-uniform
        const int cl  = (bn & 1023) + cb;
        const int r   = bmL + h * 128 + lrow;
        bf16* sel = (seg == 0) ? CqU : (seg == 1) ? CkU : CvU;
        ushort4 p; p.x = f2b(v[0]); p.y = f2b(v[1]); p.z = f2b(v[2]); p.w = f2b(v[3]);
        *(ushort4*)&sel[(size_t)r * DIM + cl] = p;
      }
    }
    __syncthreads();
  }
}

// ================= legacy 128x128 GEMM (low-ws fallback only) =================
template<int EPI, bool A_F32>
__global__ __launch_bounds__(256) void gemm_nt(
    const void* __restrict__ Ap, const bf16* __restrict__ Bt,
    int M, int N, int K,
    float scale, float* __restrict__ Cf)
{
  __shared__ bf16 As[128 * 32];
  __shared__ bf16 Bs[128 * 32];
  const int tid  = threadIdx.x;
  const int lane = tid & 63, wid = tid >> 6;
  const int wr = wid >> 1, wc = wid & 1;
  const int tilesN = N >> 7;
  const int nwg = gridDim.x;
  int bid = blockIdx.x;
  if ((nwg & 7) == 0) { const int q = nwg >> 3; bid = (bid & 7) * q + (bid >> 3); }
  const int bm = (bid / tilesN) * 128, bn = (bid % tilesN) * 128;
  f32x4 acc[4][4] = {};
  const bf16*  Ab16 = (const bf16*)Ap;
  const float* Af32 = (const float*)Ap;
  const int srow = tid >> 2, sc8 = (tid & 3) * 8;
  const int frow = tid >> 3, fc4 = (tid & 7) * 4;

  for (int k0 = 0; k0 < K; k0 += 32) {
    if (A_F32) {
      #pragma unroll
      for (int is = 0; is < 4; ++is) {
        int row = is * 32 + frow;
        const float4 v = *(const float4*)(Af32 + (size_t)(bm + row) * K + k0 + fc4);
        ushort4 p; p.x = f2b(v.x); p.y = f2b(v.y); p.z = f2b(v.z); p.w = f2b(v.w);
        *(ushort4*)(&As[row * 32 + fc4]) = p;
      }
    } else {
      #pragma unroll
      for (int is = 0; is < 2; ++is) {
        int row = is * 64 + srow;
        const bf16* g = Ab16 + (size_t)(bm + row) * K + k0 + sc8;
        __builtin_amdgcn_global_load_lds(
            (const __attribute__((address_space(1))) unsigned int*)g,
            (__attribute__((address_space(3))) unsigned int*)(&As[row * 32 + sc8]), 16, 0, 0);
      }
    }
    #pragma unroll
    for (int is = 0; is < 2; ++is) {
      int row = is * 64 + srow;
      const bf16* g = Bt + (size_t)(bn + row) * K + k0 + sc8;
      __builtin_amdgcn_global_load_lds(
          (const __attribute__((address_space(1))) unsigned int*)g,
          (__attribute__((address_space(3))) unsigned int*)(&Bs[row * 32 + sc8]), 16, 0, 0);
    }
    __syncthreads();
    const int lr = lane & 15, kg = lane >> 4;
    bf16x8 af[4], bfv[4];
    #pragma unroll
    for (int i = 0; i < 4; ++i)
      af[i] = *(const bf16x8*)(&As[(wr * 64 + i * 16 + lr) * 32 + kg * 8]);
    #pragma unroll
    for (int j = 0; j < 4; ++j)
      bfv[j] = *(const bf16x8*)(&Bs[(wc * 64 + j * 16 + lr) * 32 + kg * 8]);
    #pragma unroll
    for (int i = 0; i < 4; ++i)
      #pragma unroll
      for (int j = 0; j < 4; ++j)
        acc[i][j] = __builtin_amdgcn_mfma_f32_16x16x32_bf16(af[i], bfv[j], acc[i][j], 0, 0, 0);
    __syncthreads();
  }
  const int r0 = bm + wr * 64 + (lane >> 4) * 4;
  const int c0 = bn + wc * 64 + (lane & 15);
  if (EPI == 2) {
    #pragma unroll
    for (int i = 0; i < 4; ++i)
      #pragma unroll
      for (int j = 0; j < 4; ++j)
        #pragma unroll
        for (int e = 0; e < 4; ++e) {
          float pr = 1.0f / (1.0f + __expf(-acc[i][j][e] * scale));
          Cf[(size_t)(r0 + i * 16 + e) * N + c0 + j * 16] = pr;
        }
  } else {
    #pragma unroll
    for (int i = 0; i < 4; ++i)
      #pragma unroll
      for (int j = 0; j < 4; ++j)
        #pragma unroll
        for (int e = 0; e < 4; ++e)
          Cf[(size_t)(r0 + i * 16 + e) * N + c0 + j * 16] = acc[i][j][e];
  }
}

extern "C" void kernel_launch(void* const* d_in, const int* in_sizes, int n_in,
                              void* d_out, int out_size, void* d_ws, size_t ws_size,
                              hipStream_t stream) {
  const float* x1 = (const float*)d_in[0];
  const float* x2 = (const float*)d_in[1];
  const float* W[6] = { (const float*)d_in[2],  (const float*)d_in[4],  (const float*)d_in[6],
                        (const float*)d_in[8],  (const float*)d_in[10], (const float*)d_in[12] };
  const float* B[6] = { (const float*)d_in[3],  (const float*)d_in[5],  (const float*)d_in[7],
                        (const float*)d_in[9],  (const float*)d_in[11], (const float*)d_in[13] };

  const size_t MD = (size_t)NTOK * DIM;   // 8,388,608
  const size_t DD = (size_t)DIM * DIM;    // 1,048,576
  const size_t NN = (size_t)NTOK * NTOK;  // 67,108,864

  // ws layout (bf16 elements)
  bf16* ws   = (bf16*)d_ws;
  bf16* x1b  = ws;                         // 8M (contiguous with x2b -> proj A, M=16384)
  bf16* x2b  = x1b + MD;
  bf16* wt1  = x2b + MD;                   // [Wq1T;Wk1T;Wv1T]
  bf16* wt2  = wt1 + 3 * DD;
  float* bstack = (float*)(wt2 + 3 * DD);  // 6144 f32 in 16384-bf16 slot
  bf16* q1   = wt2 + 3 * DD + 16384;
  bf16* k1   = q1 + MD;
  bf16* q2   = k1 + MD;
  bf16* k2   = q2 + MD;
  bf16* v1r  = k2 + MD;                    // v row-major temps
  bf16* v2r  = v1r + MD;
  bf16* v1T  = v2r + MD;
  bf16* v2T  = v1T + MD;
  bf16* probsb = v2T + MD;                 // 2 x 64M bf16 (both directions)
  float* part  = (float*)(probsb + 2 * NN);// 4 x 8M f32

  const size_t topBytes = ((size_t)(12 * MD + 6 * DD + 16384) + 2 * NN) * 2 + 4 * MD * 4;
  const bool top = (ws_size >= topBytes);  // ~684 MB; measured ws ≈ 2.4 GB

  float* out    = (float*)d_out;
  float* ctx2   = out;
  float* probs2 = ctx2 + MD;
  float* ctx1   = probs2 + NN;
  float* probs1 = ctx1 + MD;

  const float scale = 1.0f / 32.0f;

  // casts + weight transposes + bias pack
  {
    int n4 = (int)(MD / 4);
    int blks = (n4 + 255) / 256;
    cast_f32_bf16<<<blks, 256, 0, stream>>>(x1, x1b, n4);
    cast_f32_bf16<<<blks, 256, 0, stream>>>(x2, x2b, n4);
  }
  {
    int blks = (DIM / 32) * (DIM / 32);
    transpose_cast32<<<blks, 256, 0, stream>>>(W[0], wt1 + 0 * DD, DIM, DIM);
    transpose_cast32<<<blks, 256, 0, stream>>>(W[1], wt1 + 1 * DD, DIM, DIM);
    transpose_cast32<<<blks, 256, 0, stream>>>(W[2], wt1 + 2 * DD, DIM, DIM);
    transpose_cast32<<<blks, 256, 0, stream>>>(W[3], wt2 + 0 * DD, DIM, DIM);
    transpose_cast32<<<blks, 256, 0, stream>>>(W[4], wt2 + 1 * DD, DIM, DIM);
    transpose_cast32<<<blks, 256, 0, stream>>>(W[5], wt2 + 2 * DD, DIM, DIM);
  }
  pack_bias<<<24, 256, 0, stream>>>(B[0], B[1], B[2], B[3], B[4], B[5], bstack);

  // fused QKV projection: A = [x1b;x2b] (16384 x 1024); q/k/v row-major out. grid 768.
  gemm256<5, false><<<64 * 12, 512, 0, stream>>>(
      x1b, wt1, nullptr, wt2, 2 * NTOK, 3 * DIM, DIM, 12, 1, 768,
      bstack, bstack + 3 * DIM, 0.f,
      nullptr, nullptr, nullptr, nullptr,
      q1, k1, v1r, q2, k2, v2r);

  // v transpose: [8192,1024] -> [1024,8192], both inputs, 4096 blocks
  transpose_bf16<<<2 * (NTOK / 64) * (DIM / 64), 256, 0, stream>>>(
      (const short*)v1r, (short*)v1T, (const short*)v2r, (short*)v2T, NTOK, DIM);

  const int perQK = (NTOK / 256) * (NTOK / 256);  // 1024
  const int perPV = (NTOK / 256) * (DIM / 256);   // 128

  if (top) {
    // fused QK (both directions, 2048 blocks):
    //   dir0: probs2 = sigmoid(s * q1@k2^T) -> f32 + bf16(probsb)
    //   dir1: probs1 = sigmoid(s * q2@k1^T) -> f32 + bf16(probsb+NN)
    gemm256<4, true><<<2 * perQK, 512, 0, stream>>>(
        q1, k2, q2, k1, NTOK, NTOK, DIM, 32, 1, perQK,
        nullptr, nullptr, scale,
        probs2, probs1, probsb, probsb + NN,
        nullptr, nullptr, nullptr, nullptr, nullptr, nullptr);
    // PV per direction (keep each 128MB probs L3-resident), split-K=2, grid 256
    gemm256<3, false><<<2 * perPV, 512, 0, stream>>>(
        probsb, v2T, nullptr, nullptr, NTOK, DIM, NTOK, 4, 2, 2 * perPV,
        nullptr, nullptr, 0.f,
        part, nullptr, nullptr, nullptr,
        nullptr, nullptr, nullptr, nullptr, nullptr, nullptr);
    gemm256<3, false><<<2 * perPV, 512, 0, stream>>>(
        probsb + NN, v1T, nullptr, nullptr, NTOK, DIM, NTOK, 4, 2, 2 * perPV,
        nullptr, nullptr, 0.f,
        part + 2 * MD, nullptr, nullptr, nullptr,
        nullptr, nullptr, nullptr, nullptr, nullptr, nullptr);
    {
      int n4 = (int)(MD / 4);
      add2_dual<<<(2 * n4 + 255) / 256, 256, 0, stream>>>(part, ctx2, ctx1, n4);
    }
  } else {
    // fallback: f32 probs only; PV re-reads f32 probs from d_out with convert-on-stage
    gemm256<2, false><<<perQK, 512, 0, stream>>>(
        q1, k2, nullptr, nullptr, NTOK, NTOK, DIM, 32, 1, perQK,
        nullptr, nullptr, scale,
        probs2, nullptr, nullptr, nullptr,
        nullptr, nullptr, nullptr, nullptr, nullptr, nullptr);
    gemm_nt<3, true><<<(NTOK / 128) * (DIM / 128), 256, 0, stream>>>(
        probs2, v2T, NTOK, DIM, NTOK, 0.f, ctx2);
    gemm256<2, false><<<perQK, 512, 0, stream>>>(
        q2, k1, nullptr, nullptr, NTOK, NTOK, DIM, 32, 1, perQK,
        nullptr, nullptr, scale,
        probs1, nullptr, nullptr, nullptr,
        nullptr, nullptr, nullptr, nullptr, nullptr, nullptr);
    gemm_nt<3, true><<<(NTOK / 128) * (DIM / 128), 256, 0, stream>>>(
        probs1, v1T, NTOK, DIM, NTOK, 0.f, ctx1);
  }
}